// Round 7
// baseline (923.778 us; speedup 1.0000x reference)
//
#include <hip/hip_runtime.h>

// Problem constants
#define Bsz 16384
#define Isz 512
#define Hsz 512
#define Ksz 1024   // I + H
#define N4H 2048   // 4*H

// GEMM tile (256x256, BK=32, 4-phase-per-K-step schedule, 64 KiB LDS)
#define BM 256
#define BN 256
#define BK 32

typedef __bf16 bf16x8 __attribute__((ext_vector_type(8)));
typedef __bf16 bf16x4 __attribute__((ext_vector_type(4)));
typedef float  f32x4  __attribute__((ext_vector_type(4)));

__device__ __forceinline__ void async_copy16(const void* g, void* l) {
    __builtin_amdgcn_global_load_lds(
        (__attribute__((address_space(1))) void*)g,
        (__attribute__((address_space(3))) void*)l,
        16, 0, 0);
}

// ---------------------------------------------------------------------------
// Combined pack kernel (round-5 config — best measured total).
// Blocks [0, 16384): activations  Aq[b][k] = bf16([input|h_prev][b][k])
// Blocks [16384, 18432): weights, gate-interleaved row permutation + bias.
//   Permuted row p: nb=p/128, n=p%128; wn=n>>6, gate=(n>>4)&3, c=n&15
//   -> original row = gate*512 + nb*32 + wn*16 + c.
// ---------------------------------------------------------------------------
__global__ void pack_all(const float* __restrict__ x, const float* __restrict__ h,
                         const float* __restrict__ Wxh, const float* __restrict__ Whh,
                         const float* __restrict__ bxh, const float* __restrict__ bhh,
                         __bf16* __restrict__ Aq, __bf16* __restrict__ Bq,
                         float* __restrict__ bias) {
    if (blockIdx.x < 16384) {
        int idx = blockIdx.x * 256 + threadIdx.x;
        int e   = idx << 2;
        int row = e >> 10, col = e & 1023;
        const float4 v = (col < Isz)
            ? *(const float4*)(x + (size_t)row * Isz + col)
            : *(const float4*)(h + (size_t)row * Hsz + (col - Isz));
        bf16x4 o = { (__bf16)v.x, (__bf16)v.y, (__bf16)v.z, (__bf16)v.w };
        *(bf16x4*)(Aq + (size_t)e) = o;
    } else {
        int idx = (blockIdx.x - 16384) * 256 + threadIdx.x;
        int p   = idx >> 8;
        int k   = (idx & 255) << 2;
        int nb  = p >> 7, n = p & 127;
        int wn  = n >> 6, t = (n >> 4) & 3, c = n & 15;
        int orow = t * Hsz + nb * 32 + wn * 16 + c;
        const float4 v = (k < Isz)
            ? *(const float4*)(Wxh + (size_t)orow * Isz + k)
            : *(const float4*)(Whh + (size_t)orow * Hsz + (k - Isz));
        bf16x4 o = { (__bf16)v.x, (__bf16)v.y, (__bf16)v.z, (__bf16)v.w };
        *(bf16x4*)(Bq + (size_t)p * Ksz + k) = o;
        if ((idx & 255) == 0) bias[p] = bxh[orow] + bhh[orow];
    }
}

// ---------------------------------------------------------------------------
// Fused GEMM + sLSTM epilogue — ROUND-7: 64 KiB LDS -> 2 blocks/CU.
//
// R6 cycle accounting: MFMA floor 8.3 us, LDS-pipe ~25 us, staging ~15 us,
// epilogue HBM ~40 us — yet gemm = 117 us. Gap = serialization at 1 block/CU
// (128 KiB LDS): phases lockstep with nothing to overlap, and the epilogue
// serializes with the K-loop. Fix: BK=32 double-buffered = 4x16 KiB = 64 KiB
// -> 2 blocks/CU (16 waves). Cross-block overlap hides ds_read/barrier time
// under the other block's MFMA and one block's epilogue under the other's
// K-loop.
//
// Schedule (4 phases per K-step, 32 steps; same discipline as the verified
// 8-phase/2-step): per phase {inline-asm ds_read | issue global_load_lds} ->
// barrier -> lgkmcnt(0)+sched_barrier(0) -> setprio(1) -> 8 MFMA ->
// setprio(0) -> barrier. vmcnt(4) ONCE per step (end of q3): every step
// issues exactly 4 loads (B h0 @q2, B h1 + A h0 + A h1 @q3, targeting step
// s+2 = same parity, issued strictly after that array's last read in this
// step); the wait retires exactly the 4 loads step s+1 needs. Tail steps
// clamp to a restage of step 31 (identical bytes -> benign).
//
// LDS layout: 128-B SUPER-ROWS (2 tile rows of 32 bf16). Super-row r2 has 8
// 16-B slots; slot p holds global (row = 2*r2 + (gp>>2), kgrp = gp&3) with
// gp = p ^ (r2&7) — same XOR class as the round-5 layout that measured 0
// bank conflicts (each slot value hit by exactly 2 lanes per 16-lane group).
// Staging keeps gload_lds dest linear (q = half*512 + tid) and pre-swizzles
// the SOURCE: gp = (tid&7)^((tid>>3)&7), row = half*128 + 2*(tid>>3)+(gp>>2),
// kcol = (gp&3)*8. Fragment reads: one lane base + f*1024 offsets.
// ---------------------------------------------------------------------------
#define CFENCE asm volatile("" ::: "memory")
#define BARRIER { CFENCE; __builtin_amdgcn_s_barrier(); CFENCE; }
#define WAITLGKM { asm volatile("s_waitcnt lgkmcnt(0)" ::: "memory"); \
                   __builtin_amdgcn_sched_barrier(0); }
#define WAITVM4  asm volatile("s_waitcnt vmcnt(4)" ::: "memory")

#define LDSA(p) ((unsigned)(size_t)(const __bf16 __attribute__((address_space(3)))*)(p))

#define DSR(dst, addr, IMM) \
    asm volatile("ds_read_b128 %0, %1 offset:" IMM : "=v"(dst) : "v"(addr))

#define LDS_A03(ab) { DSR(af[0], ab, "0");    DSR(af[1], ab, "1024"); \
                      DSR(af[2], ab, "2048"); DSR(af[3], ab, "3072"); }
#define LDS_A47(ab) { DSR(af[4], ab, "4096"); DSR(af[5], ab, "5120"); \
                      DSR(af[6], ab, "6144"); DSR(af[7], ab, "7168"); }
#define LDS_B01(bb) { DSR(bf[0], bb, "0");    DSR(bf[1], bb, "1024"); }
#define LDS_B23(bb) { DSR(bf[2], bb, "2048"); DSR(bf[3], bb, "3072"); }

#define MMA8(fb, nb)                                                          \
    __builtin_amdgcn_s_setprio(1);                                            \
    _Pragma("unroll") for (int f = 0; f < 4; ++f)                             \
    _Pragma("unroll") for (int n = 0; n < 2; ++n)                             \
        acc[(fb) + f][(nb) + n] = __builtin_amdgcn_mfma_f32_16x16x32_bf16(    \
            af[(fb) + f], bf[(nb) + n], acc[(fb) + f][(nb) + n], 0, 0, 0);    \
    __builtin_amdgcn_s_setprio(0);

// One half = 128 tile rows = 8 KiB = 1 gload_lds / thread.
#define STAGE_H(dst, srcS, half, step)                                        \
    async_copy16((srcS) + (size_t)(half) * 131072 + (step) * 32,              \
                 (char*)(dst) + (half) * 8192 + tid * 16);

__global__ __launch_bounds__(512, 4) void slstm_gemm(
    const __bf16* __restrict__ Aq, const __bf16* __restrict__ Bq,
    const float* __restrict__ bias,
    const float* __restrict__ c_prev, const float* __restrict__ m_prev,
    const float* __restrict__ n_prev, float* __restrict__ out) {

    __shared__ __bf16 As0[BM * BK];   // 16 KiB each, 64 KiB total
    __shared__ __bf16 As1[BM * BK];
    __shared__ __bf16 Bs0[BN * BK];
    __shared__ __bf16 Bs1[BN * BK];

    const int tid  = threadIdx.x;
    const int w    = tid >> 6;
    const int lane = tid & 63;
    const int wm   = w & 1;          // wave M row (0..1) -> 128 rows each
    const int wc   = w >> 1;         // wave N col (0..3) -> 64 cols each

    const int bm  = blockIdx.x;      // batch tile (0..63)
    const int nbb = blockIdx.y;      // 256-wide gate-col tile (0..7)

    const int lr = lane & 15;
    const int g0 = lane >> 4;        // 0..3  (k-group of this lane's MFMA slice)

    const __bf16* Ag = Aq + (size_t)bm  * BM * Ksz;
    const __bf16* Bg = Bq + (size_t)nbb * BN * Ksz;

    // Staging source pre-swizzle (see header): gp, row base, k col.
    const int sgp  = (tid & 7) ^ ((tid >> 3) & 7);
    const int sr0  = ((tid >> 3) << 1) + (sgp >> 2);
    const int skc  = (sgp & 3) << 3;
    const __bf16* AgS = Ag + (size_t)sr0 * Ksz + skc;
    const __bf16* BgS = Bg + (size_t)sr0 * Ksz + skc;

    // Fragment-read lane base: super-row = tilerow>>1, slot = gp^(r2&7).
    const int p_rd = (((lr & 1) << 2) | g0) ^ ((lr >> 1) & 7);
    const unsigned aoff = (unsigned)((wm * 64 + (lr >> 1)) * 128 + p_rd * 16);
    const unsigned boff = (unsigned)((wc * 32 + (lr >> 1)) * 128 + p_rd * 16);
    const unsigned a0b = LDSA(As0) + aoff, a1b = LDSA(As1) + aoff;
    const unsigned b0b = LDSA(Bs0) + boff, b1b = LDSA(Bs1) + boff;

    f32x4 acc[8][4];
    const f32x4 zero = {0.f, 0.f, 0.f, 0.f};
#pragma unroll
    for (int mi = 0; mi < 8; ++mi)
#pragma unroll
        for (int ni = 0; ni < 4; ++ni) acc[mi][ni] = zero;

    // ---- prologue: stage steps 0 (even bufs) and 1 (odd bufs) ----
    STAGE_H(As0, AgS, 0, 0); STAGE_H(As0, AgS, 1, 0);
    STAGE_H(Bs0, BgS, 0, 0); STAGE_H(Bs0, BgS, 1, 0);
    STAGE_H(As1, AgS, 0, 1); STAGE_H(As1, AgS, 1, 1);
    STAGE_H(Bs1, BgS, 0, 1); STAGE_H(Bs1, BgS, 1, 1);
    WAITVM4;            // step 0 complete; step 1 (4 loads) in flight
    BARRIER;

    bf16x8 af[8];
    bf16x8 bf[4];

#pragma unroll 1
    for (int it = 0; it < 16; ++it) {
        const int t0 = (it < 15) ? 2 * it + 2 : 31;   // stage target, even step
        const int t1 = (it < 15) ? 2 * it + 3 : 31;   // stage target, odd step
        __bf16* Ad0 = (it < 15) ? As0 : As1;          // tail restage -> odd bufs
        __bf16* Bd0 = (it < 15) ? Bs0 : Bs1;

        // ================ step s0 = 2*it (even buffers) ================
        // q0: A[0..3], B[0..1]
        LDS_A03(a0b); LDS_B01(b0b);
        BARRIER; WAITLGKM;
        MMA8(0, 0);
        BARRIER;
        // q1: B[2..3]
        LDS_B23(b0b);
        BARRIER; WAITLGKM;
        MMA8(0, 2);
        BARRIER;
        // q2: A[4..7]; stage B(t0) h0 (B-array last read was q1)
        LDS_A47(a0b);
        STAGE_H(Bd0, BgS, 0, t0);
        BARRIER; WAITLGKM;
        MMA8(4, 2);
        BARRIER;
        // q3: stage B(t0) h1, A(t0) h0/h1 (A-array last read was q2)
        STAGE_H(Bd0, BgS, 1, t0);
        STAGE_H(Ad0, AgS, 0, t0);
        STAGE_H(Ad0, AgS, 1, t0);
        BARRIER;
        MMA8(4, 0);
        WAITVM4;        // retire step s0+1's 4 loads; 4 stay in flight
        BARRIER;

        // ================ step s1 = 2*it+1 (odd buffers) ================
        LDS_A03(a1b); LDS_B01(b1b);
        BARRIER; WAITLGKM;
        MMA8(0, 0);
        BARRIER;
        LDS_B23(b1b);
        BARRIER; WAITLGKM;
        MMA8(0, 2);
        BARRIER;
        LDS_A47(a1b);
        STAGE_H(Bs1, BgS, 0, t1);
        BARRIER; WAITLGKM;
        MMA8(4, 2);
        BARRIER;
        STAGE_H(Bs1, BgS, 1, t1);
        STAGE_H(As1, AgS, 0, t1);
        STAGE_H(As1, AgS, 1, t1);
        BARRIER;
        MMA8(4, 0);
        WAITVM4;        // retire step s1+1's 4 loads; 4 stay in flight
        BARRIER;
    }

    // ---------------- fused sLSTM epilogue (fast-math) ----------------------
    // Wave wc's 4 N-fragments are the 4 gates of the same 16 h values.
    const int hidx = (nbb * 2 + (wc >> 1)) * 32 + (wc & 1) * 16 + lr;

    float bsv[4];
#pragma unroll
    for (int n = 0; n < 4; ++n)
        bsv[n] = bias[nbb * 256 + wc * 64 + n * 16 + lr];

    const size_t BH = (size_t)Bsz * Hsz;
    const float L2E  = 1.44269504089f;   // log2(e)
    const float L2E2 = 2.88539008178f;   // 2*log2(e)

#pragma unroll
    for (int mi = 0; mi < 8; ++mi) {
        const int mbase = bm * 256 + wm * 128 + mi * 16 + g0 * 4;
#pragma unroll
        for (int r = 0; r < 4; ++r) {
            const int m = mbase + r;
            const size_t off = (size_t)m * Hsz + hidx;
            const float ig = acc[mi][0][r] + bsv[0];
            const float fg = acc[mi][1][r] + bsv[1];
            const float zg = acc[mi][2][r] + bsv[2];
            const float og = acc[mi][3][r] + bsv[3];
            const float cp = c_prev[off];
            const float mp = m_prev[off];
            const float np = n_prev[off];
            // tanh(zg) = 1 - 2/(exp2(2*zg*log2e)+1)  (saturates to +-1 cleanly)
            const float zt = 1.f - 2.f * __builtin_amdgcn_rcpf(
                                 __builtin_amdgcn_exp2f(zg * L2E2) + 1.f);
            // sigmoid(og) = 1/(1+exp2(-og*log2e))
            const float ot = __builtin_amdgcn_rcpf(
                                 __builtin_amdgcn_exp2f(-og * L2E) + 1.f);
            const float fm = fg + mp;
            const float mt = fmaxf(fm, ig);
            const float it2 = __builtin_amdgcn_exp2f((ig - mt) * L2E);
            const float ft  = __builtin_amdgcn_exp2f((fm - mt) * L2E);
            const float ct = ft * cp + it2 * zt;
            const float nt = ft * np + it2;
            const float ht = ot * ct * __builtin_amdgcn_rcpf(nt);
            out[off]          = ht;
            out[BH + off]     = ct;
            out[2 * BH + off] = mt;
            out[3 * BH + off] = nt;
        }
    }
}

// ---------------------------------------------------------------------------
extern "C" void kernel_launch(void* const* d_in, const int* in_sizes, int n_in,
                              void* d_out, int out_size, void* d_ws, size_t ws_size,
                              hipStream_t stream) {
    const float* input  = (const float*)d_in[0];
    const float* h_prev = (const float*)d_in[1];
    const float* c_prev = (const float*)d_in[2];
    const float* m_prev = (const float*)d_in[3];
    const float* n_prev = (const float*)d_in[4];
    const float* Wxh    = (const float*)d_in[5];
    const float* bxh    = (const float*)d_in[6];
    const float* Whh    = (const float*)d_in[7];
    const float* bhh    = (const float*)d_in[8];
    float* out = (float*)d_out;

    // Workspace layout: Aq (32 MiB bf16) | Bq (4 MiB bf16) | bias (8 KiB f32)
    __bf16* Aq   = (__bf16*)d_ws;
    __bf16* Bq   = (__bf16*)((char*)d_ws + (size_t)Bsz * Ksz * 2);
    float*  bias = (float*)((char*)d_ws + (size_t)Bsz * Ksz * 2 + (size_t)N4H * Ksz * 2);

    pack_all<<<16384 + 2048, 256, 0, stream>>>(input, h_prev, Wxh, Whh, bxh, bhh,
                                               Aq, Bq, bias);

    dim3 grid(Bsz / BM, N4H / BN);
    slstm_gemm<<<grid, 512, 0, stream>>>(Aq, Bq, bias, c_prev, m_prev, n_prev, out);
}